// Round 3
// baseline (680.564 us; speedup 1.0000x reference)
//
#include <hip/hip_runtime.h>

#define NH 10
#define NB 8        // batches
#define NC 8        // channels
#define NT 16384    // targets
#define NS 4096     // sources
#define EPSW 1e-10f
#define CAP 192     // per-target candidate capacity; E[cand]=40.7, sd~6.4 -> P(>CAP)~0
#define T2  0.02f   // d^2 threshold: P(chi2_2 < 0.02) ~= 0.00995 -> E[cand] ~= 40.7

typedef float float4n __attribute__((ext_vector_type(4)));

// Branch-free ascending sorted insert of a u64 key (d2bits<<32 | idx).
// Key ordering == (d2 asc, idx asc): exact jax top_k tie-breaking for free.
__device__ __forceinline__ void insert_key(unsigned long long key, unsigned long long kv[NH]) {
    bool c[NH];
#pragma unroll
    for (int k = 0; k < NH; ++k) c[k] = key < kv[k];
    unsigned long long nv[NH];
    nv[0] = c[0] ? key : kv[0];
#pragma unroll
    for (int k = 1; k < NH; ++k)
        nv[k] = c[k] ? (c[k - 1] ? kv[k - 1] : key) : kv[k];
#pragma unroll
    for (int k = 0; k < NH; ++k) kv[k] = nv[k];
}

// One 256-thread block per target. Each lane owns 8 float4s (16 sources),
// all 8 loads in flight at once -> max MLP, no serial latency chain.
__global__ __launch_bounds__(256) void knn_interp_kernel(
    const float* __restrict__ x,    // [NB, NS, NC]
    const float* __restrict__ rel,  // [NT, NS, 2]
    float* __restrict__ out)        // [NB, NT, NC]
{
    const int tid  = threadIdx.x;
    const int lane = tid & 63;
    const int t    = blockIdx.x;

    __shared__ unsigned long long cb[CAP];
    __shared__ int scnt;
    if (tid == 0) scnt = 0;
    __syncthreads();

    const float4n* relrow = (const float4n*)(rel + (size_t)t * (NS * 2));
    const unsigned long long lmask = (1ull << lane) - 1ull;

    // ---- issue all 8 cached loads up front (8 outstanding per lane) ----
    float4n q[8];
#pragma unroll
    for (int k = 0; k < 8; ++k)
        q[k] = relrow[k * 256 + tid];

    // ---- filter + ballot-compact candidates into block-shared buffer ----
    auto compact = [&](float d2, int ix) {
        unsigned long long m = __ballot(d2 < T2);
        if (m) {                                   // wave-uniform branch
            int base = 0;
            if (lane == 0) base = atomicAdd(&scnt, (int)__popcll(m));
            base = __shfl(base, 0, 64);
            if (d2 < T2) {
                int pos = base + (int)__popcll(m & lmask);
                if (pos < CAP)
                    cb[pos] = ((unsigned long long)__float_as_uint(d2) << 32) | (unsigned)ix;
            }
        }
    };

#pragma unroll
    for (int k = 0; k < 8; ++k) {
        const int f = k * 256 + tid;   // f4 index; covers elements 2f, 2f+1
        float d2a = q[k].x * q[k].x + q[k].y * q[k].y;
        float d2b = q[k].z * q[k].z + q[k].w * q[k].w;
        compact(d2a, 2 * f);
        compact(d2b, 2 * f + 1);
    }

    __syncthreads();           // cb[] + scnt visible
    const int cnt = scnt;

    if (tid >= 64) return;     // wave 0 finishes the target; others retire

    unsigned long long kv[NH];
#pragma unroll
    for (int k = 0; k < NH; ++k) kv[k] = ~0ull;

    if (cnt >= NH && cnt <= CAP) {
        // >= NH elements strictly below T2 => global top-NH all inside cb[0..cnt)
        for (int i = lane; i < cnt; i += 64)
            insert_key(cb[i], kv);
    } else {
        // exact fallback for arbitrary data (P ~ 1e-9/target on this distribution)
        for (int f = lane; f < NS / 2; f += 64) {
            float4n qq = relrow[f];
            float d2a = qq.x * qq.x + qq.y * qq.y;
            float d2b = qq.z * qq.z + qq.w * qq.w;
            insert_key(((unsigned long long)__float_as_uint(d2a) << 32) | (unsigned)(2 * f),     kv);
            insert_key(((unsigned long long)__float_as_uint(d2b) << 32) | (unsigned)(2 * f + 1), kv);
        }
    }

    // ---- wave all-reduce: global top-NH via u64 key min-extract, NH rounds ----
    float rd[NH];
    int   ridx[NH];
#pragma unroll
    for (int r = 0; r < NH; ++r) {
        unsigned long long m = kv[0];
#pragma unroll
        for (int o = 32; o > 0; o >>= 1) {
            unsigned long long other = __shfl_xor(m, o, 64);
            m = (other < m) ? other : m;
        }
        rd[r]   = __uint_as_float((unsigned)(m >> 32));
        ridx[r] = (int)(unsigned)(m & 0xFFFFFFFFull);
        bool won = (kv[0] == m);  // unique idx in key -> exactly one winner
#pragma unroll
        for (int k = 0; k < NH - 1; ++k) kv[k] = won ? kv[k + 1] : kv[k];
        kv[NH - 1] = won ? ~0ull : kv[NH - 1];
    }

    // ---- weights ----
    float w[NH];
    float wsum = 0.f;
#pragma unroll
    for (int r = 0; r < NH; ++r) {
        float d = sqrtf(rd[r]);
        w[r] = 1.0f / (d + EPSW);
        wsum += w[r];
    }
    const float inv = 1.0f / wsum;

    // ---- gather + weighted sum: lane = b*8 + c covers all (b,c) pairs ----
    const int b = lane >> 3;
    const int c = lane & 7;
    const float* xb = x + ((size_t)b * NS) * NC + c;
    float acc = 0.f;
#pragma unroll
    for (int r = 0; r < NH; ++r) {
        acc += w[r] * xb[(size_t)ridx[r] * NC];
    }
    out[((size_t)b * NT + t) * NC + c] = acc * inv;
}

extern "C" void kernel_launch(void* const* d_in, const int* in_sizes, int n_in,
                              void* d_out, int out_size, void* d_ws, size_t ws_size,
                              hipStream_t stream) {
    const float* x   = (const float*)d_in[0];
    const float* rel = (const float*)d_in[1];
    float* out = (float*)d_out;

    dim3 grid(NT);       // one 256-thread block per target
    dim3 block(256);
    knn_interp_kernel<<<grid, block, 0, stream>>>(x, rel, out);
}